// Round 1
// baseline (77.252 us; speedup 1.0000x reference)
//
#include <hip/hip_runtime.h>
#include <math.h>

// Problem constants (from reference setup_inputs)
#define B   64
#define NJ  42
#define NP  16384
#define CHUNKS 8
#define PC  (NP / CHUNKS)   // 2048 points per block
#define TPB 256
#define PPT (PC / TPB)      // 8 points per thread
#define RSTRIDE 260         // 260 floats = 1040 B = 65*16 B: float4-aligned rows, stride%32=4 banks

__global__ __launch_bounds__(TPB) void sdl_min_kernel(
    const float* __restrict__ joints,   // [B, NJ, 3]
    const float* __restrict__ pts,      // [B, NP, 3]
    unsigned int* __restrict__ wmin)    // [B*NJ] float-as-uint running min of clamped d^2
{
    __shared__ __align__(16) float4 sj[NJ];               // joint xyz + |a|^2
    __shared__ __align__(16) float  red[NJ * RSTRIDE];    // transpose reduction scratch

    const int tid = threadIdx.x;
    const int b   = blockIdx.x / CHUNKS;
    const int ch  = blockIdx.x % CHUNKS;

    // Stage joints: xyz and precomputed |a|^2 in .w
    if (tid < NJ) {
        const float* jp = joints + (b * NJ + tid) * 3;
        float x = jp[0], y = jp[1], z = jp[2];
        sj[tid] = make_float4(x, y, z, fmaf(x, x, fmaf(y, y, z * z)));
    }
    __syncthreads();

    // Load 8 points/thread into registers, precompute |p|^2
    float px[PPT], py[PPT], pz[PPT], p2[PPT];
    const float* pb = pts + (size_t)(b * NP + ch * PC) * 3;
#pragma unroll
    for (int k = 0; k < PPT; ++k) {
        int idx = (k * TPB + tid) * 3;       // coalesced per k-slice
        float x = pb[idx], y = pb[idx + 1], z = pb[idx + 2];
        px[k] = x; py[k] = y; pz[k] = z;
        p2[k] = fmaf(x, x, fmaf(y, y, z * z));
    }

    // Per-thread running mins of (|p|^2 - 2 a.p); |a|^2 added after reduction.
    float m[NJ];
#pragma unroll
    for (int j = 0; j < NJ; ++j) m[j] = 3.0e38f;

#pragma unroll
    for (int j = 0; j < NJ; ++j) {
        float4 Jv = sj[j];                   // one ds_read_b128, amortized over 8 points
#pragma unroll
        for (int k = 0; k < PPT; ++k) {
            float s = fmaf(px[k], Jv.x, fmaf(py[k], Jv.y, pz[k] * Jv.z));
            float v = fmaf(-2.0f, s, p2[k]);
            m[j] = fminf(m[j], v);
        }
    }

    // Block reduction via LDS transpose: thread t writes column t of 42 rows
    // (consecutive-lane addresses -> conflict-free), then threads 0..41 each
    // min-reduce their own row with float4 reads.
#pragma unroll
    for (int j = 0; j < NJ; ++j) red[j * RSTRIDE + tid] = m[j];
    __syncthreads();

    if (tid < NJ) {
        const float4* row = (const float4*)(red + tid * RSTRIDE);
        float4 a = row[0];
        for (int i = 1; i < TPB / 4; ++i) {
            float4 v = row[i];
            a.x = fminf(a.x, v.x); a.y = fminf(a.y, v.y);
            a.z = fminf(a.z, v.z); a.w = fminf(a.w, v.w);
        }
        float mn = fminf(fminf(a.x, a.y), fminf(a.z, a.w));
        float d2 = fmaxf(mn + sj[tid].w, 0.0f);   // clamp commutes with min
        atomicMin(wmin + b * NJ + tid, __float_as_uint(d2));
    }
}

__global__ __launch_bounds__(256) void sdl_final_kernel(
    const unsigned int* __restrict__ wmin,  // [B*NJ] clamped min d^2 (>=0) as uint bits
    const float* __restrict__ gt,           // [B*NJ]
    float* __restrict__ out)                // [1]
{
    const int tid = threadIdx.x;
    float acc = 0.0f;
    for (int i = tid; i < B * NJ; i += 256) {
        float d    = sqrtf(__uint_as_float(wmin[i]));
        float diff = d - gt[i];
        acc = fmaf(diff, diff, acc);
    }
#pragma unroll
    for (int off = 32; off > 0; off >>= 1)
        acc += __shfl_xor(acc, off);
    __shared__ float wsum[4];
    if ((tid & 63) == 0) wsum[tid >> 6] = acc;
    __syncthreads();
    if (tid == 0)
        out[0] = (wsum[0] + wsum[1] + wsum[2] + wsum[3]) * (1.0f / (B * NJ));
}

extern "C" void kernel_launch(void* const* d_in, const int* in_sizes, int n_in,
                              void* d_out, int out_size, void* d_ws, size_t ws_size,
                              hipStream_t stream) {
    const float* pred = (const float*)d_in[0];   // [B,NJ,3]
    const float* obj  = (const float*)d_in[1];   // [B,NP,3]
    const float* gt   = (const float*)d_in[2];   // [B,NJ]
    unsigned int* wmin = (unsigned int*)d_ws;    // B*NJ uints

    // 0x7F7F7F7F == 3.39e38f: valid "+inf-ish" init for float-as-uint atomicMin
    hipMemsetAsync(wmin, 0x7F, B * NJ * sizeof(unsigned int), stream);
    sdl_min_kernel<<<B * CHUNKS, TPB, 0, stream>>>(pred, obj, wmin);
    sdl_final_kernel<<<1, 256, 0, stream>>>(wmin, gt, (float*)d_out);
}

// Round 2
// 73.116 us; speedup vs baseline: 1.0566x; 1.0566x over previous
//
#include <hip/hip_runtime.h>
#include <math.h>

// Problem constants (from reference setup_inputs)
#define B   64
#define NJ  42
#define NP  16384
#define CHUNKS 8
#define PC  (NP / CHUNKS)   // 2048 points per block
#define TPB 256
#define PPT (PC / TPB)      // 8 points per thread
#define NPAIR (PPT / 2)     // 4 float2 pairs per thread
#define RSTRIDE 260         // row stride (floats): 260*4B, consecutive-lane writes conflict-free

typedef float v2f __attribute__((ext_vector_type(2)));

// Per-(b,chunk) block: min over its 2048 points of (0.5*|p|^2 - a.p) for all
// 42 joints, finalized to clamped d^2 and stored as a partial (no atomics).
__global__ __launch_bounds__(TPB) void sdl_min_kernel(
    const float* __restrict__ joints,   // [B, NJ, 3]
    const float* __restrict__ pts,      // [B, NP, 3]
    float* __restrict__ part)           // [CHUNKS][B*NJ] partial clamped d^2
{
    __shared__ __align__(16) float4 sj[NJ];               // joint xyz + |a|^2
    __shared__ __align__(16) float  red[NJ * RSTRIDE];    // transpose reduction scratch

    const int tid = threadIdx.x;
    const int b   = blockIdx.x >> 3;    // / CHUNKS
    const int ch  = blockIdx.x & 7;     // % CHUNKS

    // Stage joints: xyz and |a|^2
    if (tid < NJ) {
        const float* jp = joints + (b * NJ + tid) * 3;
        float x = jp[0], y = jp[1], z = jp[2];
        sj[tid] = make_float4(x, y, z, fmaf(x, x, fmaf(y, y, z * z)));
    }

    // Load 8 points/thread as 4 float2 pairs: store NEGATED coords and
    // q = 0.5*|p|^2 so the inner loop is a pure 3-FMA chain:
    //   q - a.p  ==  fma(-px,ax, fma(-py,ay, fma(-pz,az, q)))
    v2f npx[NPAIR], npy[NPAIR], npz[NPAIR], q[NPAIR];
    const float* pb = pts + (size_t)(b * NP + ch * PC) * 3;
#pragma unroll
    for (int k = 0; k < NPAIR; ++k) {
        int i0 = ((2 * k)     * TPB + tid) * 3;   // coalesced k-slices
        int i1 = ((2 * k + 1) * TPB + tid) * 3;
        float x0 = pb[i0], y0 = pb[i0 + 1], z0 = pb[i0 + 2];
        float x1 = pb[i1], y1 = pb[i1 + 1], z1 = pb[i1 + 2];
        npx[k] = (v2f){-x0, -x1};
        npy[k] = (v2f){-y0, -y1};
        npz[k] = (v2f){-z0, -z1};
        q[k]   = (v2f){0.5f * fmaf(x0, x0, fmaf(y0, y0, z0 * z0)),
                       0.5f * fmaf(x1, x1, fmaf(y1, y1, z1 * z1))};
    }
    __syncthreads();

    // Per-thread running min of (q - a.p) per joint.
    float m[NJ];
#pragma unroll
    for (int j = 0; j < NJ; ++j) m[j] = 3.0e38f;

#pragma unroll
    for (int j = 0; j < NJ; ++j) {
        float4 Jv = sj[j];                 // broadcast ds_read_b128
        v2f jx = (v2f){Jv.x, Jv.x};
        v2f jy = (v2f){Jv.y, Jv.y};
        v2f jz = (v2f){Jv.z, Jv.z};
        float mj = m[j];
#pragma unroll
        for (int k = 0; k < NPAIR; ++k) {
            v2f t = npz[k] * jz + q[k];    // v_pk_fma_f32 (ffp-contract=fast)
            t     = npy[k] * jy + t;
            t     = npx[k] * jx + t;
            mj = fminf(fminf(mj, t.x), t.y);   // -> v_min3_f32
        }
        m[j] = mj;
    }

    // Block reduction via LDS transpose: conflict-free column writes,
    // then threads 0..41 min-reduce their own row with float4 reads.
#pragma unroll
    for (int j = 0; j < NJ; ++j) red[j * RSTRIDE + tid] = m[j];
    __syncthreads();

    if (tid < NJ) {
        const float4* row = (const float4*)(red + tid * RSTRIDE);
        float4 a = row[0];
        for (int i = 1; i < TPB / 4; ++i) {
            float4 v = row[i];
            a.x = fminf(a.x, v.x); a.y = fminf(a.y, v.y);
            a.z = fminf(a.z, v.z); a.w = fminf(a.w, v.w);
        }
        float mn = fminf(fminf(a.x, a.y), fminf(a.z, a.w));
        // d^2 = 2*min(q - a.p) + |a|^2, clamped (commutes with min)
        float d2 = fmaxf(fmaf(2.0f, mn, sj[tid].w), 0.0f);
        part[ch * (B * NJ) + b * NJ + tid] = d2;
    }
}

__global__ __launch_bounds__(1024) void sdl_final_kernel(
    const float* __restrict__ part,   // [CHUNKS][B*NJ]
    const float* __restrict__ gt,     // [B*NJ]
    float* __restrict__ out)          // [1]
{
    const int tid = threadIdx.x;
    float acc = 0.0f;
    for (int i = tid; i < B * NJ; i += 1024) {
        float mn = part[i];
#pragma unroll
        for (int c = 1; c < CHUNKS; ++c) mn = fminf(mn, part[c * (B * NJ) + i]);
        float diff = sqrtf(mn) - gt[i];
        acc = fmaf(diff, diff, acc);
    }
#pragma unroll
    for (int off = 32; off > 0; off >>= 1)
        acc += __shfl_xor(acc, off);
    __shared__ float wsum[16];
    if ((tid & 63) == 0) wsum[tid >> 6] = acc;
    __syncthreads();
    if (tid == 0) {
        float s = 0.0f;
#pragma unroll
        for (int w = 0; w < 16; ++w) s += wsum[w];
        out[0] = s * (1.0f / (B * NJ));
    }
}

extern "C" void kernel_launch(void* const* d_in, const int* in_sizes, int n_in,
                              void* d_out, int out_size, void* d_ws, size_t ws_size,
                              hipStream_t stream) {
    const float* pred = (const float*)d_in[0];   // [B,NJ,3]
    const float* obj  = (const float*)d_in[1];   // [B,NP,3]
    const float* gt   = (const float*)d_in[2];   // [B,NJ]
    float* part = (float*)d_ws;                  // CHUNKS*B*NJ floats (86 KB)

    sdl_min_kernel<<<B * CHUNKS, TPB, 0, stream>>>(pred, obj, part);
    sdl_final_kernel<<<1, 1024, 0, stream>>>(part, gt, (float*)d_out);
}